// Round 3
// baseline (394.836 us; speedup 1.0000x reference)
//
#include <hip/hip_runtime.h>
#include <stdint.h>

// Problem constants
#define NB 8
#define NC 256
#define NN 16384

typedef short bf16x8 __attribute__((ext_vector_type(8)));  // 8 bf16 = 4 VGPR
typedef float f32x4  __attribute__((ext_vector_type(4)));
typedef uint32_t u32;

__device__ __forceinline__ unsigned short f2bf(float f) {
  union { float f; unsigned u; } c; c.f = f;
  return (unsigned short)((c.u + 0x7FFFu + ((c.u >> 16) & 1u)) >> 16);  // RNE
}

// async global->LDS, 16B per lane; LDS dest is wave-uniform base + lane*16
__device__ __forceinline__ void gload16(const void* g, void* l) {
  __builtin_amdgcn_global_load_lds(
      (const __attribute__((address_space(1))) u32*)g,
      (__attribute__((address_space(3))) u32*)l, 16, 0, 0);
}

// Stage a [128 rows x 64 bf16] tile (row stride ld_bytes) into 16KB of LDS.
// T2 XOR-swizzle applied on the per-lane global source; LDS stays linear.
__device__ __forceinline__ void stage_tile(const char* src, int ld_bytes,
                                           char* lds, int w, int l) {
#pragma unroll
  for (int i = 0; i < 4; ++i) {
    int s = (w * 4 + i) * 64 + l;      // 0..1023 : 16B chunk index
    int row = s >> 3;
    int srcslot = (l & 7) ^ (row & 7);
    gload16(src + (size_t)row * ld_bytes + srcslot * 16,
            lds + (w * 4 + i) * 1024);
  }
}

// m97-style TN GEMM core: C[128,128] += A[128,K] * B[128,K]^T, K = ktiles*64.
// 256 threads = 4 waves as 2x2, each wave 64x64 via 4x4 frags of 16x16x32 bf16.
__device__ __forceinline__ void gemm_core(const char* A, int lda_b,
                                          const char* Bm, int ldb_b, int ktiles,
                                          char* smem, int tid, f32x4 acc[4][4]) {
  const int w = tid >> 6, l = tid & 63;
  const int wm = w >> 1, wn = w & 1;
  char* As = smem;
  char* Bs = smem + 16384;
  for (int kt = 0; kt < ktiles; ++kt) {
    stage_tile(A + kt * 128, lda_b, As, w, l);
    stage_tile(Bm + kt * 128, ldb_b, Bs, w, l);
    __syncthreads();
#pragma unroll
    for (int ks = 0; ks < 2; ++ks) {
      bf16x8 av[4], bv[4];
      const int kb = ks * 64 + ((l >> 4) << 4);
#pragma unroll
      for (int m = 0; m < 4; ++m) {
        int row = wm * 64 + m * 16 + (l & 15);
        av[m] = *(const bf16x8*)(As + row * 128 + (kb ^ ((row & 7) << 4)));
      }
#pragma unroll
      for (int nq = 0; nq < 4; ++nq) {
        int row = wn * 64 + nq * 16 + (l & 15);
        bv[nq] = *(const bf16x8*)(Bs + row * 128 + (kb ^ ((row & 7) << 4)));
      }
#pragma unroll
      for (int m = 0; m < 4; ++m)
#pragma unroll
        for (int nq = 0; nq < 4; ++nq)
          acc[m][nq] = __builtin_amdgcn_mfma_f32_16x16x32_bf16(
              av[m], bv[nq], acc[m][nq], 0, 0, 0);
    }
    __syncthreads();
  }
}

// ---- scaled fp32 weights: Wq2, Wk2 (row-major), WkT (transposed), Wv2 ------
__global__ __launch_bounds__(256) void k_prepw2(const float* __restrict__ wqkv,
                                                const float* __restrict__ wdw,
                                                float* __restrict__ Wq2,
                                                float* __restrict__ Wk2,
                                                float* __restrict__ WkT,
                                                float* __restrict__ Wv2) {
  const int r = blockIdx.x, t = threadIdx.x;
  Wq2[r * 256 + t] = wqkv[r * 256 + t] * wdw[r];
  float kv = wqkv[(256 + r) * 256 + t] * wdw[256 + r];
  Wk2[r * 256 + t] = kv;
  WkT[t * 256 + r] = kv;
  Wv2[r * 256 + t] = wqkv[(512 + r) * 256 + t] * wdw[512 + r];
}

// ---- x fp32 -> xb bf16 [b][c][n]  AND  xt bf16 [b][n][c] -------------------
__global__ __launch_bounds__(256) void k_convert(const float* __restrict__ x,
                                                 char* __restrict__ xb,
                                                 char* __restrict__ xt) {
  __shared__ float t[64][68];  // +4 pad
  const int tid = threadIdx.x;
  const int ntile = blockIdx.x, ctile = blockIdx.y, b = blockIdx.z;
  {
    int r = tid >> 2, q = (tid & 3) * 16;
    const size_t rowoff = ((size_t)(b * NC + ctile * 64 + r)) * NN + ntile * 64 + q;
    const float* src = x + rowoff;
    unsigned short bv[16] __attribute__((aligned(16)));
#pragma unroll
    for (int i = 0; i < 4; ++i) {
      float4 v = *(const float4*)(src + i * 4);
      *(float4*)&t[r][q + i * 4] = v;
      bv[i * 4 + 0] = f2bf(v.x);
      bv[i * 4 + 1] = f2bf(v.y);
      bv[i * 4 + 2] = f2bf(v.z);
      bv[i * 4 + 3] = f2bf(v.w);
    }
    char* dst = xb + rowoff * 2;
    *(uint4*)(dst) = *(const uint4*)(bv);
    *(uint4*)(dst + 16) = *(const uint4*)(bv + 8);
  }
  __syncthreads();
  {
    int nl = tid >> 2, cq = (tid & 3) * 16;
    unsigned short outv[16] __attribute__((aligned(16)));
#pragma unroll
    for (int i = 0; i < 16; ++i) outv[i] = f2bf(t[cq + i][nl]);
    char* dst = xt + (((size_t)b * NN + ntile * 64 + nl) * NC + ctile * 64 + cq) * 2;
    *(uint4*)(dst) = *(const uint4*)(outv);
    *(uint4*)(dst + 16) = *(const uint4*)(outv + 8);
  }
}

// ---- Gram partials: Gpart[ks][b][c][d] = x_chunk @ x_chunk^T ---------------
__global__ __launch_bounds__(256) void k_gram(const char* __restrict__ xb,
                                              float* __restrict__ gpart) {
  __shared__ char smem[32768];
  const int tid = threadIdx.x;
  const int mt = blockIdx.x & 1, dt = blockIdx.x >> 1;
  const int ks = blockIdx.y, b = blockIdx.z;
  f32x4 acc[4][4];
#pragma unroll
  for (int m = 0; m < 4; ++m)
#pragma unroll
    for (int nq = 0; nq < 4; ++nq) acc[m][nq] = (f32x4){0.f, 0.f, 0.f, 0.f};
  const char* Ap = xb + ((size_t)(b * NC + mt * 128) * NN + (size_t)ks * 2048) * 2;
  const char* Bp = xb + ((size_t)(b * NC + dt * 128) * NN + (size_t)ks * 2048) * 2;
  gemm_core(Ap, NN * 2, Bp, NN * 2, 32, smem, tid, acc);
  const int w = tid >> 6, l = tid & 63, wm = w >> 1, wn = w & 1;
#pragma unroll
  for (int m = 0; m < 4; ++m)
#pragma unroll
    for (int nq = 0; nq < 4; ++nq)
#pragma unroll
      for (int r = 0; r < 4; ++r) {
        int c = mt * 128 + wm * 64 + m * 16 + ((l >> 4) << 2) + r;
        int d = dt * 128 + wn * 64 + nq * 16 + (l & 15);
        gpart[(((size_t)ks * NB + b) * 256 + c) * 256 + d] = acc[m][nq][r];
      }
}

// ---- G[b] = sum_ks Gpart --------------------------------------------------
__global__ __launch_bounds__(256) void k_reduceG(const float* __restrict__ gpart,
                                                 float* __restrict__ G) {
  const int t = threadIdx.x, c = blockIdx.x, b = blockIdx.y;
  float s = 0.f;
#pragma unroll
  for (int ks = 0; ks < 8; ++ks)
    s += gpart[(((size_t)ks * NB + b) * 256 + c) * 256 + t];
  G[((size_t)b * 256 + c) * 256 + t] = s;
}

// ---- generic small fp32 GEMM: C[b] = A[b] @ B[b] (256x256x256) -------------
// A row-major [256][K=256], B row-major [K=256][256]. Batch strides in elems.
__global__ __launch_bounds__(256) void k_smallgemm(
    const float* __restrict__ A, long aBS,
    const float* __restrict__ Bm, long bBS,
    char* __restrict__ C, long cBS, int out_bf16) {
  __shared__ float wt[32 * 256];
  __shared__ float at[32 * 256];
  const int t = threadIdx.x;
  const int o0 = blockIdx.x * 32, b = blockIdx.y;
  const float* Ab = A + (size_t)b * aBS;
  const float* Bb = Bm + (size_t)b * bBS;
#pragma unroll
  for (int i = 0; i < 32; ++i) wt[i * 256 + t] = Ab[(size_t)(o0 + i) * 256 + t];
  float acc[32];
#pragma unroll
  for (int o = 0; o < 32; ++o) acc[o] = 0.f;
  for (int ch = 0; ch < 8; ++ch) {
    __syncthreads();
#pragma unroll
    for (int j = 0; j < 32; ++j)
      at[j * 256 + t] = Bb[(size_t)(ch * 32 + j) * 256 + t];
    __syncthreads();
    for (int j = 0; j < 32; ++j) {
      float a = at[j * 256 + t];
#pragma unroll
      for (int o = 0; o < 32; ++o) acc[o] += wt[o * 256 + ch * 32 + j] * a;
    }
  }
  if (out_bf16) {
    unsigned short* Cp = (unsigned short*)C + (size_t)b * cBS;
#pragma unroll
    for (int o = 0; o < 32; ++o) Cp[(size_t)(o0 + o) * 256 + t] = f2bf(acc[o]);
  } else {
    float* Cp = (float*)C + (size_t)b * cBS;
#pragma unroll
    for (int o = 0; o < 32; ++o) Cp[(size_t)(o0 + o) * 256 + t] = acc[o];
  }
}

// ---- norms: nq[b][c] = T1[b][c]·Wq2[c], nk[b][d] = T2[b][d]·Wk2[d] ---------
__global__ __launch_bounds__(256) void k_norms(const float* __restrict__ T1,
                                               const float* __restrict__ T2,
                                               const float* __restrict__ Wq2,
                                               const float* __restrict__ Wk2,
                                               float* __restrict__ nq,
                                               float* __restrict__ nk) {
  const int w = threadIdx.x >> 6, l = threadIdx.x & 63;
  const int gid = blockIdx.x * 4 + w;      // 0..4095
  const int qk = gid >> 11, b = (gid >> 8) & 7, c = gid & 255;
  const float* T = qk ? T2 : T1;
  const float* W = qk ? Wk2 : Wq2;
  float s = 0.f;
#pragma unroll
  for (int j = 0; j < 4; ++j)
    s += T[((size_t)b * 256 + c) * 256 + j * 64 + l] * W[c * 256 + j * 64 + l];
#pragma unroll
  for (int off = 32; off; off >>= 1) s += __shfl_xor(s, off);
  if (l == 0) (qk ? nk : nq)[b * 256 + c] = s;
}

// ---- softmax over d: attn[b][c][d] -----------------------------------------
__global__ __launch_bounds__(256) void k_softmax(const float* __restrict__ S,
                                                 const float* __restrict__ nq,
                                                 const float* __restrict__ nk,
                                                 const float* __restrict__ temp,
                                                 float* __restrict__ attn) {
  const int d = threadIdx.x, c = blockIdx.x, b = blockIdx.y;
  float s = S[((size_t)b * 256 + c) * 256 + d];
  float rq = 1.0f / fmaxf(sqrtf(nq[b * 256 + c]), 1e-12f);
  float rk = 1.0f / fmaxf(sqrtf(nk[b * 256 + d]), 1e-12f);
  float logit = s * rq * rk * temp[0];
  float m = logit;
#pragma unroll
  for (int off = 32; off; off >>= 1) m = fmaxf(m, __shfl_xor(m, off));
  __shared__ float red[4];
  __shared__ float red2[4];
  const int w = d >> 6, l = d & 63;
  if (l == 0) red[w] = m;
  __syncthreads();
  m = fmaxf(fmaxf(red[0], red[1]), fmaxf(red[2], red[3]));
  float e = __expf(logit - m);
  float t2 = e;
#pragma unroll
  for (int off = 32; off; off >>= 1) t2 += __shfl_xor(t2, off);
  if (l == 0) red2[w] = t2;
  __syncthreads();
  float tot = red2[0] + red2[1] + red2[2] + red2[3];
  attn[((size_t)b * 256 + c) * 256 + d] = e / tot;
}

// ---- final: out[b][o][n] = F[b] @ x[b] ; computed as outT tiles ------------
// A = xt (rows n, K=c contiguous), B = F bf16 (rows o, K=c contiguous).
__global__ __launch_bounds__(256) void k_final(const char* __restrict__ xt,
                                               const char* __restrict__ fb,
                                               float* __restrict__ out) {
  __shared__ char smem[65536];
  const int tid = threadIdx.x;
  const int nt = blockIdx.x, ot = blockIdx.y, b = blockIdx.z;
  f32x4 acc[4][4];
#pragma unroll
  for (int m = 0; m < 4; ++m)
#pragma unroll
    for (int nq = 0; nq < 4; ++nq) acc[m][nq] = (f32x4){0.f, 0.f, 0.f, 0.f};
  const char* Ap = xt + ((size_t)b * NN + (size_t)nt * 128) * 512;
  const char* Bp = fb + ((size_t)(b * 256 + ot * 128)) * 512;
  gemm_core(Ap, 512, Bp, 512, 4, smem, tid, acc);
  const int w = tid >> 6, l = tid & 63, wm = w >> 1, wn = w & 1;
  // bounce transposed into LDS: [o_local 128][n_local 128] fp32, swizzled
#pragma unroll
  for (int m = 0; m < 4; ++m)
#pragma unroll
    for (int nq = 0; nq < 4; ++nq)
#pragma unroll
      for (int r = 0; r < 4; ++r) {
        int i = wm * 64 + m * 16 + ((l >> 4) << 2) + r;  // n_local (A row)
        int j = wn * 64 + nq * 16 + (l & 15);            // o_local (B row)
        *(float*)(smem + j * 512 + ((i * 4) ^ ((j & 7) << 4))) = acc[m][nq][r];
      }
  __syncthreads();
  const int j = tid >> 1, h = tid & 1;
  float* dst = out + ((size_t)(b * 256 + ot * 128 + j)) * NN + nt * 128;
#pragma unroll
  for (int cc = 0; cc < 16; ++cc) {
    int ch = h * 16 + cc;
    *(uint4*)(dst + ch * 4) =
        *(const uint4*)(smem + j * 512 + ((ch * 16) ^ ((j & 7) << 4)));
  }
}

extern "C" void kernel_launch(void* const* d_in, const int* in_sizes, int n_in,
                              void* d_out, int out_size, void* d_ws, size_t ws_size,
                              hipStream_t stream) {
  const float* x     = (const float*)d_in[0];
  const float* wqkv  = (const float*)d_in[1];
  const float* wdwf  = (const float*)d_in[2];
  const float* temp  = (const float*)d_in[3];
  const float* wproj = (const float*)d_in[4];
  float* out = (float*)d_out;
  char* ws = (char*)d_ws;

  // Workspace layout (bytes)
  char*  xb    = ws;                            // bf16 [B][C][N]     67,108,864
  char*  xt    = ws + 67108864;                 // bf16 [B][N][C]     67,108,864
  float* gpart = (float*)(ws + 134217728);      // f32 [8][B][256][256] 67,108,864
  float* G     = (float*)(ws + 201326592);      // f32 [B][256][256]   2,097,152
  float* T1    = (float*)(ws + 203423744);      // f32 [B][256][256]   2,097,152
  float* T2    = (float*)(ws + 205520896);      // f32 [B][256][256]   2,097,152
  float* S     = (float*)(ws + 207618048);      // f32 [B][256][256]   2,097,152
  float* attn  = (float*)(ws + 209715200);      // f32 [B][256][256]   2,097,152
  float* F1    = (float*)(ws + 211812352);      // f32 [B][256][256]   2,097,152
  char*  Fb    = ws + 213909504;                // bf16 [B][256][256]  1,048,576
  float* Wq2   = (float*)(ws + 214958080);      // f32 [256][256]        262,144
  float* Wk2   = (float*)(ws + 215220224);      // f32 [256][256]        262,144
  float* WkT   = (float*)(ws + 215482368);      // f32 [256][256]        262,144
  float* Wv2   = (float*)(ws + 215744512);      // f32 [256][256]        262,144
  float* nq    = (float*)(ws + 216006656);      // f32 [B][256]            8,192
  float* nk    = (float*)(ws + 216014848);      // f32 [B][256]            8,192
  // total: 216,023,040 bytes

  k_prepw2<<<dim3(256), dim3(256), 0, stream>>>(wqkv, wdwf, Wq2, Wk2, WkT, Wv2);
  k_convert<<<dim3(256, 4, 8), dim3(256), 0, stream>>>(x, xb, xt);
  k_gram<<<dim3(4, 8, 8), dim3(256), 0, stream>>>(xb, gpart);
  k_reduceG<<<dim3(256, 8), dim3(256), 0, stream>>>(gpart, G);
  // T1 = Wq2 @ G ; T2 = Wk2 @ G
  k_smallgemm<<<dim3(8, 8), dim3(256), 0, stream>>>(Wq2, 0L, G, 65536L,
                                                    (char*)T1, 65536L, 0);
  k_smallgemm<<<dim3(8, 8), dim3(256), 0, stream>>>(Wk2, 0L, G, 65536L,
                                                    (char*)T2, 65536L, 0);
  k_norms<<<dim3(1024), dim3(256), 0, stream>>>(T1, T2, Wq2, Wk2, nq, nk);
  // S = T1 @ Wk2^T  (B = WkT row-major [e][d])
  k_smallgemm<<<dim3(8, 8), dim3(256), 0, stream>>>(T1, 65536L, WkT, 0L,
                                                    (char*)S, 65536L, 0);
  k_softmax<<<dim3(256, 8), dim3(256), 0, stream>>>(S, nq, nk, temp, attn);
  // F1 = attn @ Wv2 ; F = Wp @ F1 (bf16)
  k_smallgemm<<<dim3(8, 8), dim3(256), 0, stream>>>(attn, 65536L, Wv2, 0L,
                                                    (char*)F1, 65536L, 0);
  k_smallgemm<<<dim3(8, 8), dim3(256), 0, stream>>>(wproj, 0L, F1, 65536L,
                                                    Fb, 65536L, 1);  // FIX: was 32768
  k_final<<<dim3(128, 2, 8), dim3(256), 0, stream>>>(xt, Fb, out);
}

// Round 4
// 275.019 us; speedup vs baseline: 1.4357x; 1.4357x over previous
//
#include <hip/hip_runtime.h>
#include <stdint.h>

// Problem constants
#define NB 8
#define NC 256
#define NN 16384

typedef short bf16x8 __attribute__((ext_vector_type(8)));  // 8 bf16 = 4 VGPR
typedef float f32x4  __attribute__((ext_vector_type(4)));
typedef uint32_t u32;

__device__ __forceinline__ unsigned short f2bf(float f) {
  union { float f; unsigned u; } c; c.f = f;
  return (unsigned short)((c.u + 0x7FFFu + ((c.u >> 16) & 1u)) >> 16);  // RNE
}

// async global->LDS, 16B per lane; LDS dest is wave-uniform base + lane*16
__device__ __forceinline__ void gload16(const void* g, void* l) {
  __builtin_amdgcn_global_load_lds(
      (const __attribute__((address_space(1))) u32*)g,
      (__attribute__((address_space(3))) u32*)l, 16, 0, 0);
}

// Stage a [128 rows x 64 bf16] tile (row stride ld_bytes) into 16KB of LDS.
// T2 XOR-swizzle applied on the per-lane global source; LDS stays linear.
__device__ __forceinline__ void stage_tile(const char* src, int ld_bytes,
                                           char* lds, int w, int l) {
#pragma unroll
  for (int i = 0; i < 4; ++i) {
    int s = (w * 4 + i) * 64 + l;      // 0..1023 : 16B chunk index
    int row = s >> 3;
    int srcslot = (l & 7) ^ (row & 7);
    gload16(src + (size_t)row * ld_bytes + srcslot * 16,
            lds + (w * 4 + i) * 1024);
  }
}

// m97-style TN GEMM core: C[128,128] += A[128,K] * B[128,K]^T, K = ktiles*64.
__device__ __forceinline__ void gemm_core(const char* A, int lda_b,
                                          const char* Bm, int ldb_b, int ktiles,
                                          char* smem, int tid, f32x4 acc[4][4]) {
  const int w = tid >> 6, l = tid & 63;
  const int wm = w >> 1, wn = w & 1;
  char* As = smem;
  char* Bs = smem + 16384;
  for (int kt = 0; kt < ktiles; ++kt) {
    stage_tile(A + kt * 128, lda_b, As, w, l);
    stage_tile(Bm + kt * 128, ldb_b, Bs, w, l);
    __syncthreads();
#pragma unroll
    for (int ks = 0; ks < 2; ++ks) {
      bf16x8 av[4], bv[4];
      const int kb = ks * 64 + ((l >> 4) << 4);
#pragma unroll
      for (int m = 0; m < 4; ++m) {
        int row = wm * 64 + m * 16 + (l & 15);
        av[m] = *(const bf16x8*)(As + row * 128 + (kb ^ ((row & 7) << 4)));
      }
#pragma unroll
      for (int nq = 0; nq < 4; ++nq) {
        int row = wn * 64 + nq * 16 + (l & 15);
        bv[nq] = *(const bf16x8*)(Bs + row * 128 + (kb ^ ((row & 7) << 4)));
      }
#pragma unroll
      for (int m = 0; m < 4; ++m)
#pragma unroll
        for (int nq = 0; nq < 4; ++nq)
          acc[m][nq] = __builtin_amdgcn_mfma_f32_16x16x32_bf16(
              av[m], bv[nq], acc[m][nq], 0, 0, 0);
    }
    __syncthreads();
  }
}

// ---- scaled fp32 weights: Wq2 | Wk2 contiguous (=Wcat), WkT, Wv2 -----------
__global__ __launch_bounds__(256) void k_prepw2(const float* __restrict__ wqkv,
                                                const float* __restrict__ wdw,
                                                float* __restrict__ Wq2,
                                                float* __restrict__ Wk2,
                                                float* __restrict__ WkT,
                                                float* __restrict__ Wv2) {
  const int r = blockIdx.x, t = threadIdx.x;
  Wq2[r * 256 + t] = wqkv[r * 256 + t] * wdw[r];
  float kv = wqkv[(256 + r) * 256 + t] * wdw[256 + r];
  Wk2[r * 256 + t] = kv;
  WkT[t * 256 + r] = kv;
  Wv2[r * 256 + t] = wqkv[(512 + r) * 256 + t] * wdw[512 + r];
}

// ---- x fp32 -> xb bf16 [b][c][n]  AND  xt bf16 [b][n][c] -------------------
// LDS pad 65 (odd): all accesses <=2-way bank aliasing (free, m136).
__global__ __launch_bounds__(256) void k_convert(const float* __restrict__ x,
                                                 char* __restrict__ xb,
                                                 char* __restrict__ xt) {
  __shared__ float t[64][65];
  const int tid = threadIdx.x;
  const int ntile = blockIdx.x, ctile = blockIdx.y, b = blockIdx.z;
  {
    int r = tid >> 2, q = (tid & 3) * 16;
    const size_t rowoff = ((size_t)(b * NC + ctile * 64 + r)) * NN + ntile * 64 + q;
    const float* src = x + rowoff;
    unsigned short bv[16] __attribute__((aligned(16)));
#pragma unroll
    for (int i = 0; i < 4; ++i) {
      float4 v = *(const float4*)(src + i * 4);
      t[r][q + i * 4 + 0] = v.x;
      t[r][q + i * 4 + 1] = v.y;
      t[r][q + i * 4 + 2] = v.z;
      t[r][q + i * 4 + 3] = v.w;
      bv[i * 4 + 0] = f2bf(v.x);
      bv[i * 4 + 1] = f2bf(v.y);
      bv[i * 4 + 2] = f2bf(v.z);
      bv[i * 4 + 3] = f2bf(v.w);
    }
    char* dst = xb + rowoff * 2;
    *(uint4*)(dst) = *(const uint4*)(bv);
    *(uint4*)(dst + 16) = *(const uint4*)(bv + 8);
  }
  __syncthreads();
  {
    int nl = tid >> 2, cq = (tid & 3) * 16;
    unsigned short outv[16] __attribute__((aligned(16)));
#pragma unroll
    for (int i = 0; i < 16; ++i) outv[i] = f2bf(t[cq + i][nl]);
    char* dst = xt + (((size_t)b * NN + ntile * 64 + nl) * NC + ctile * 64 + cq) * 2;
    *(uint4*)(dst) = *(const uint4*)(outv);
    *(uint4*)(dst + 16) = *(const uint4*)(outv + 8);
  }
}

// ---- Gram partials: Gpart[ks][b][c][d] = x_chunk @ x_chunk^T (KS=8) --------
__global__ __launch_bounds__(256) void k_gram(const char* __restrict__ xb,
                                              float* __restrict__ gpart) {
  __shared__ char smem[32768];
  const int tid = threadIdx.x;
  const int mt = blockIdx.x & 1, dt = blockIdx.x >> 1;
  const int ks = blockIdx.y, b = blockIdx.z;
  f32x4 acc[4][4];
#pragma unroll
  for (int m = 0; m < 4; ++m)
#pragma unroll
    for (int nq = 0; nq < 4; ++nq) acc[m][nq] = (f32x4){0.f, 0.f, 0.f, 0.f};
  const char* Ap = xb + ((size_t)(b * NC + mt * 128) * NN + (size_t)ks * 2048) * 2;
  const char* Bp = xb + ((size_t)(b * NC + dt * 128) * NN + (size_t)ks * 2048) * 2;
  gemm_core(Ap, NN * 2, Bp, NN * 2, 32, smem, tid, acc);
  const int w = tid >> 6, l = tid & 63, wm = w >> 1, wn = w & 1;
#pragma unroll
  for (int m = 0; m < 4; ++m)
#pragma unroll
    for (int nq = 0; nq < 4; ++nq)
#pragma unroll
      for (int r = 0; r < 4; ++r) {
        int c = mt * 128 + wm * 64 + m * 16 + ((l >> 4) << 2) + r;
        int d = dt * 128 + wn * 64 + nq * 16 + (l & 15);
        gpart[(((size_t)ks * NB + b) * 256 + c) * 256 + d] = acc[m][nq][r];
      }
}

// ---- G[b] = sum_ks Gpart ---------------------------------------------------
__global__ __launch_bounds__(256) void k_reduceG(const float* __restrict__ gpart,
                                                 float* __restrict__ G) {
  const int t = threadIdx.x, c = blockIdx.x, b = blockIdx.y;
  float s = 0.f;
#pragma unroll
  for (int ks = 0; ks < 8; ++ks)
    s += gpart[(((size_t)ks * NB + b) * 256 + c) * 256 + t];
  G[((size_t)b * 256 + c) * 256 + t] = s;
}

// ---- small fp32 GEMM, no LDS / no barriers: C[b][o0+o][t] = A.B ------------
// Thread t owns column t and 8 rows. A-reads wave-uniform (scalar cached),
// B-reads coalesced (L2/L3-hot), B value register-reused across 8 rows.
// grid (M/8, NB), block 256.
__global__ __launch_bounds__(256) void k_sg(const float* __restrict__ A, long aBS,
                                            const float* __restrict__ Bm, long bBS,
                                            char* __restrict__ C, long cBS,
                                            int out_bf16) {
  const int t = threadIdx.x;
  const int o0 = blockIdx.x * 8, b = blockIdx.y;
  const float* Ab = A + (size_t)b * aBS + (size_t)o0 * 256;
  const float* Bb = Bm + (size_t)b * bBS + t;
  float acc[8];
#pragma unroll
  for (int o = 0; o < 8; ++o) acc[o] = 0.f;
#pragma unroll 4
  for (int k = 0; k < 256; ++k) {
    float bv = Bb[(size_t)k * 256];
#pragma unroll
    for (int o = 0; o < 8; ++o) acc[o] += Ab[o * 256 + k] * bv;
  }
  if (out_bf16) {
    unsigned short* Cp = (unsigned short*)C + (size_t)b * cBS;
#pragma unroll
    for (int o = 0; o < 8; ++o) Cp[(size_t)(o0 + o) * 256 + t] = f2bf(acc[o]);
  } else {
    float* Cp = (float*)C + (size_t)b * cBS;
#pragma unroll
    for (int o = 0; o < 8; ++o) Cp[(size_t)(o0 + o) * 256 + t] = acc[o];
  }
}

// ---- norms from T12 diag: nqk[b][r] = dot(T12[b][r], Wcat[r]) --------------
__global__ __launch_bounds__(256) void k_norms2(const float* __restrict__ T12,
                                                const float* __restrict__ Wcat,
                                                float* __restrict__ nqk) {
  const int w = threadIdx.x >> 6, l = threadIdx.x & 63;
  const int id = blockIdx.x * 4 + w;        // 0..4095
  const int b = id >> 9, r = id & 511;
  float s = 0.f;
#pragma unroll
  for (int j = 0; j < 4; ++j)
    s += T12[(size_t)b * 131072 + r * 256 + j * 64 + l] * Wcat[r * 256 + j * 64 + l];
#pragma unroll
  for (int off = 32; off; off >>= 1) s += __shfl_xor(s, off);
  if (l == 0) nqk[b * 512 + r] = s;
}

// ---- S = T1 @ Wk2^T fused with scaling + row-softmax -> attn ---------------
// grid (32, 8): 8 c-rows per block; thread t = column d.
__global__ __launch_bounds__(256) void k_ssoft(const float* __restrict__ T12,
                                               const float* __restrict__ WkT,
                                               const float* __restrict__ nqk,
                                               const float* __restrict__ temp,
                                               float* __restrict__ attn) {
  const int t = threadIdx.x;
  const int c0 = blockIdx.x * 8, b = blockIdx.y;
  const float* Ab = T12 + (size_t)b * 131072 + (size_t)c0 * 256;  // T1 rows
  const float* Bb = WkT + t;
  float acc[8];
#pragma unroll
  for (int o = 0; o < 8; ++o) acc[o] = 0.f;
#pragma unroll 4
  for (int k = 0; k < 256; ++k) {
    float bv = Bb[(size_t)k * 256];
#pragma unroll
    for (int o = 0; o < 8; ++o) acc[o] += Ab[o * 256 + k] * bv;
  }
  // logits: S * invnorm(q_c) * invnorm(k_d) * tau
  const float rk = 1.0f / fmaxf(sqrtf(fmaxf(nqk[b * 512 + 256 + t], 0.f)), 1e-12f);
  const float tau = temp[0];
#pragma unroll
  for (int o = 0; o < 8; ++o) {
    float rq = 1.0f / fmaxf(sqrtf(fmaxf(nqk[b * 512 + c0 + o], 0.f)), 1e-12f);
    acc[o] = acc[o] * rq * rk * tau;
  }
  // row-wise softmax over t (256 threads): shuffle + LDS combine
  __shared__ float redm[8][4];
  __shared__ float reds[8][4];
  const int w = t >> 6, l = t & 63;
#pragma unroll
  for (int o = 0; o < 8; ++o) {
    float m = acc[o];
#pragma unroll
    for (int off = 32; off; off >>= 1) m = fmaxf(m, __shfl_xor(m, off));
    if (l == 0) redm[o][w] = m;
  }
  __syncthreads();
  float e[8];
#pragma unroll
  for (int o = 0; o < 8; ++o) {
    float m = fmaxf(fmaxf(redm[o][0], redm[o][1]), fmaxf(redm[o][2], redm[o][3]));
    e[o] = __expf(acc[o] - m);
    float s = e[o];
#pragma unroll
    for (int off = 32; off; off >>= 1) s += __shfl_xor(s, off);
    if (l == 0) reds[o][w] = s;
  }
  __syncthreads();
#pragma unroll
  for (int o = 0; o < 8; ++o) {
    float tot = reds[o][0] + reds[o][1] + reds[o][2] + reds[o][3];
    attn[(size_t)b * 65536 + (size_t)(c0 + o) * 256 + t] = e[o] / tot;
  }
}

// ---- final: out[b][o][n] = F[b] @ x[b] ; computed as outT tiles ------------
__global__ __launch_bounds__(256) void k_final(const char* __restrict__ xt,
                                               const char* __restrict__ fb,
                                               float* __restrict__ out) {
  __shared__ char smem[65536];
  const int tid = threadIdx.x;
  const int nt = blockIdx.x, ot = blockIdx.y, b = blockIdx.z;
  f32x4 acc[4][4];
#pragma unroll
  for (int m = 0; m < 4; ++m)
#pragma unroll
    for (int nq = 0; nq < 4; ++nq) acc[m][nq] = (f32x4){0.f, 0.f, 0.f, 0.f};
  const char* Ap = xt + ((size_t)b * NN + (size_t)nt * 128) * 512;
  const char* Bp = fb + ((size_t)(b * 256 + ot * 128)) * 512;
  gemm_core(Ap, 512, Bp, 512, 4, smem, tid, acc);
  const int w = tid >> 6, l = tid & 63, wm = w >> 1, wn = w & 1;
  // bounce transposed into LDS: [o_local 128][n_local 128] fp32, swizzled
#pragma unroll
  for (int m = 0; m < 4; ++m)
#pragma unroll
    for (int nq = 0; nq < 4; ++nq)
#pragma unroll
      for (int r = 0; r < 4; ++r) {
        int i = wm * 64 + m * 16 + ((l >> 4) << 2) + r;  // n_local (A row)
        int j = wn * 64 + nq * 16 + (l & 15);            // o_local (B row)
        *(float*)(smem + j * 512 + ((i * 4) ^ ((j & 7) << 4))) = acc[m][nq][r];
      }
  __syncthreads();
  const int j = tid >> 1, h = tid & 1;
  float* dst = out + ((size_t)(b * 256 + ot * 128 + j)) * NN + nt * 128;
#pragma unroll
  for (int cc = 0; cc < 16; ++cc) {
    int ch = h * 16 + cc;
    *(uint4*)(dst + ch * 4) =
        *(const uint4*)(smem + j * 512 + ((ch * 16) ^ ((j & 7) << 4)));
  }
}

extern "C" void kernel_launch(void* const* d_in, const int* in_sizes, int n_in,
                              void* d_out, int out_size, void* d_ws, size_t ws_size,
                              hipStream_t stream) {
  const float* x     = (const float*)d_in[0];
  const float* wqkv  = (const float*)d_in[1];
  const float* wdwf  = (const float*)d_in[2];
  const float* temp  = (const float*)d_in[3];
  const float* wproj = (const float*)d_in[4];
  float* out = (float*)d_out;
  char* ws = (char*)d_ws;

  // Workspace layout (bytes); total ~163.6 MB
  char*  xb    = ws;                            // bf16 [B][C][N]     67,108,864
  char*  xt    = ws + 67108864;                 // bf16 [B][N][C]     67,108,864
  float* gpart = (float*)(ws + 134217728);      // f32 [8][B][256][256] 16,777,216
  float* G     = (float*)(ws + 150994944);      // f32 [B][256][256]   2,097,152
  float* T12   = (float*)(ws + 153092096);      // f32 [B][512][256]   4,194,304
  float* attn  = (float*)(ws + 157286400);      // f32 [B][256][256]   2,097,152
  float* F1    = (float*)(ws + 159383552);      // f32 [B][256][256]   2,097,152
  char*  Fb    = ws + 161480704;                // bf16 [B][256][256]  1,048,576
  float* Wq2   = (float*)(ws + 162529280);      // f32 [256][256]  (Wcat rows 0-255)
  float* Wk2   = (float*)(ws + 162791424);      // f32 [256][256]  (Wcat rows 256-511)
  float* WkT   = (float*)(ws + 163053568);      // f32 [256][256]
  float* Wv2   = (float*)(ws + 163315712);      // f32 [256][256]
  float* nqk   = (float*)(ws + 163577856);      // f32 [B][512]

  k_prepw2<<<dim3(256), dim3(256), 0, stream>>>(wqkv, wdwf, Wq2, Wk2, WkT, Wv2);
  k_convert<<<dim3(256, 4, 8), dim3(256), 0, stream>>>(x, xb, xt);
  k_gram<<<dim3(4, 8, 8), dim3(256), 0, stream>>>(xb, gpart);
  k_reduceG<<<dim3(256, 8), dim3(256), 0, stream>>>(gpart, G);
  // T12 = [Wq2;Wk2] @ G   (M=512)
  k_sg<<<dim3(64, 8), dim3(256), 0, stream>>>(Wq2, 0L, G, 65536L,
                                              (char*)T12, 131072L, 0);
  k_norms2<<<dim3(1024), dim3(256), 0, stream>>>(T12, Wq2, nqk);
  // S = T1 @ Wk2^T, fused scaling + softmax -> attn
  k_ssoft<<<dim3(32, 8), dim3(256), 0, stream>>>(T12, WkT, nqk, temp, attn);
  // F1 = attn @ Wv2 ; F = Wp @ F1 (bf16)
  k_sg<<<dim3(32, 8), dim3(256), 0, stream>>>((const float*)attn, 65536L, Wv2, 0L,
                                              (char*)F1, 65536L, 0);
  k_sg<<<dim3(32, 8), dim3(256), 0, stream>>>(wproj, 0L, F1, 65536L,
                                              Fb, 65536L, 1);
  k_final<<<dim3(128, 2, 8), dim3(256), 0, stream>>>(xt, Fb, out);
}